// Round 1
// baseline (35838.971 us; speedup 1.0000x reference)
//
#include <hip/hip_runtime.h>

// Problem constants (B=16, N=M=1024, D=32)
constexpr int   NN       = 1024;
constexpr float EPSf     = 1e-3f;
constexpr int   MAX_ITER = 100;

// exp2-domain scale: x = (v - C) * (1/eps) * log2(e)
#define K2      1442.6950408889634f
#define LN2f    0.6931471805599453f
#define INV_LN2 1.4426950408889634f
#define INV_EPS 1000.0f
#define LOGK    (-6.9314616f)   // log(1/1024 + 1e-8)

// hardware transcendentals (avoid libm name collisions)
#define EXP2F(x) __builtin_amdgcn_exp2f(x)   // 2^x
#define LOG2F(x) __builtin_amdgcn_logf(x)    // log2(x)

typedef _Float16 half8 __attribute__((ext_vector_type(8)));

// ---------------------------------------------------------------------------
// dist[b][p][q] = sum_d (A[b][p][d] - Bm[b][q][d])^2, stored fp16.
// build_dist(y,x) produces the bitwise-consistent transpose.  (unchanged)
// ---------------------------------------------------------------------------
__global__ __launch_bounds__(256) void build_dist(
    const float* __restrict__ A, const float* __restrict__ Bm,
    _Float16* __restrict__ out)
{
    __shared__ float aLds[16 * 32];
    __shared__ float bLds[256 * 33];
    const int b  = blockIdx.x >> 6;       // 16 * 64 blocks
    const int pt = blockIdx.x & 63;
    const int t  = threadIdx.x;

    const float* Ab = A  + ((size_t)b * NN + pt * 16) * 32;
    const float* Bb = Bm + (size_t)b * NN * 32;

    if (t < 128) ((float4*)aLds)[t] = ((const float4*)Ab)[t];

    for (int qt = 0; qt < 4; ++qt) {
        __syncthreads();
        const float4* src = (const float4*)(Bb + qt * 256 * 32);
#pragma unroll
        for (int i = 0; i < 8; ++i) {
            int j = t + (i << 8);
            float4 val = src[j];
            int q = j >> 3, dd = (j & 7) << 2;
            float* dst = &bLds[q * 33 + dd];
            dst[0] = val.x; dst[1] = val.y; dst[2] = val.z; dst[3] = val.w;
        }
        __syncthreads();

        float br[32];
#pragma unroll
        for (int d = 0; d < 32; ++d) br[d] = bLds[t * 33 + d];

#pragma unroll
        for (int p = 0; p < 16; ++p) {
            float acc = 0.f;
#pragma unroll
            for (int d4 = 0; d4 < 8; ++d4) {
                float4 a4 = ((const float4*)(aLds + p * 32))[d4];
                float dx = a4.x - br[d4 * 4 + 0];
                float dy = a4.y - br[d4 * 4 + 1];
                float dz = a4.z - br[d4 * 4 + 2];
                float dw = a4.w - br[d4 * 4 + 3];
                acc += dx * dx + dy * dy + dz * dz + dw * dw;
            }
            out[((size_t)b * NN + pt * 16 + p) * NN + qt * 256 + t] = (_Float16)acc;
        }
    }
}

// ---------------------------------------------------------------------------
// One 2-row LSE half-step for one wave — math bit-identical to the previous
// lse_pass body (fast M-shifted exp2 path + classic max-shifted fallback).
// Returns the err contribution (nonzero only on lane 0, when do_err).
// ---------------------------------------------------------------------------
__device__ __forceinline__ float half_step(
    const _Float16* __restrict__ Cb,     // batch base of C (or CT)
    const float* __restrict__ vkLds,     // staged vecin * K2 (1024 floats)
    float* __restrict__ outb,            // batch base of vec being updated
    int r, int lane, int do_err)
{
    const half8* r0 = (const half8*)(Cb + (size_t)r * NN);
    const half8* r1 = (const half8*)(Cb + (size_t)(r + 1) * NN);
    const float4* V4 = (const float4*)vkLds;

    const float uo0 = outb[r], uo1 = outb[r + 1];
    const float M0 = (LOGK - uo0 * INV_EPS) * INV_LN2;
    const float M1 = (LOGK - uo1 * INV_EPS) * INV_LN2;

    float x0[16], x1[16];
#pragma unroll
    for (int k = 0; k < 2; ++k) {
        const int m_ = lane + (k << 6);
        half8 c0 = r0[m_];
        half8 c1 = r1[m_];
        float4 va = V4[2 * m_], vb = V4[2 * m_ + 1];
        float vv[8] = {va.x, va.y, va.z, va.w, vb.x, vb.y, vb.z, vb.w};
#pragma unroll
        for (int j = 0; j < 8; ++j) {
            x0[8 * k + j] = fmaf((float)c0[j], -K2, vv[j]);
            x1[8 * k + j] = fmaf((float)c1[j], -K2, vv[j]);
        }
    }
    float s0 = 0.f, s1 = 0.f;
#pragma unroll
    for (int i = 0; i < 16; ++i) {
        s0 += EXP2F(x0[i] - M0);
        s1 += EXP2F(x1[i] - M1);
    }
#pragma unroll
    for (int off = 32; off > 0; off >>= 1) {
        s0 += __shfl_xor(s0, off);
        s1 += __shfl_xor(s1, off);
    }

    float lse2_0, lse2_1;
    if (__builtin_expect(!(s0 >= 1e-27f && s0 <= 1e38f) ||
                         !(s1 >= 1e-27f && s1 <= 1e38f), 0)) {
        // fallback: classic max-shifted LSE (fires at it=0 and on drift)
        float m0 = x0[0], m1 = x1[0];
#pragma unroll
        for (int i = 1; i < 16; ++i) { m0 = fmaxf(m0, x0[i]); m1 = fmaxf(m1, x1[i]); }
#pragma unroll
        for (int off = 32; off > 0; off >>= 1) {
            m0 = fmaxf(m0, __shfl_xor(m0, off));
            m1 = fmaxf(m1, __shfl_xor(m1, off));
        }
        float t0 = 0.f, t1 = 0.f;
#pragma unroll
        for (int i = 0; i < 16; ++i) { t0 += EXP2F(x0[i] - m0); t1 += EXP2F(x1[i] - m1); }
#pragma unroll
        for (int off = 32; off > 0; off >>= 1) {
            t0 += __shfl_xor(t0, off);
            t1 += __shfl_xor(t1, off);
        }
        lse2_0 = m0 + LOG2F(t0);
        lse2_1 = m1 + LOG2F(t1);
    } else {
        lse2_0 = M0 + LOG2F(s0);
        lse2_1 = M1 + LOG2F(s1);
    }

    float werr = 0.f;
    if (lane == 0) {
        float n0 = EPSf * (LOGK - lse2_0 * LN2f);
        float n1 = EPSf * (LOGK - lse2_1 * LN2f);
        if (do_err) werr = fabsf(n0 - uo0) + fabsf(n1 - uo1);
        outb[r]     = n0;
        outb[r + 1] = n1;
    }
    return werr;
}

// ---------------------------------------------------------------------------
// Sense-reversing per-batch barrier (64 blocks/batch), device-scope atomics.
// Release fence before arrive, acquire fence after wake — publishes the u/v
// writes across XCDs (per-XCD L2s are not cross-coherent).
// ---------------------------------------------------------------------------
__device__ __forceinline__ void batch_barrier(int* cnt, int* gen, int tid)
{
    __syncthreads();
    if (tid == 0) {
        __threadfence();   // release: write back this block's u/v stores
        int g = __hip_atomic_load(gen, __ATOMIC_RELAXED, __HIP_MEMORY_SCOPE_AGENT);
        int a = __hip_atomic_fetch_add(cnt, 1, __ATOMIC_ACQ_REL, __HIP_MEMORY_SCOPE_AGENT);
        if (a == 63) {
            __hip_atomic_store(cnt, 0, __ATOMIC_RELAXED, __HIP_MEMORY_SCOPE_AGENT);
            __hip_atomic_fetch_add(gen, 1, __ATOMIC_RELEASE, __HIP_MEMORY_SCOPE_AGENT);
        } else {
            while (__hip_atomic_load(gen, __ATOMIC_RELAXED, __HIP_MEMORY_SCOPE_AGENT) == g)
                __builtin_amdgcn_s_sleep(2);
        }
        __threadfence();   // acquire: invalidate stale L1/L2 before reads
    }
    __syncthreads();
}

// ---------------------------------------------------------------------------
// Persistent Sinkhorn loop: all 100 iterations in ONE launch.
// Grid 1024 x 256 = 4 blocks/CU x 256 CUs (all co-resident by construction:
// __launch_bounds__(256,4) caps VGPR at 128; LDS 4.2 KB/block).
// Block (b = blk>>6, l = blk&63) owns rows l*16..l*16+15 of batch b, as two
// sequential 8-row chunks identical to the old lse_pass layout.
// Sync: per-batch barrier after each half-step (only the 64 blocks of a batch
// share data); the global done-flag uses a per-iteration counter polled off
// the critical path (the v-phase runs between err writes and the flag read).
// ---------------------------------------------------------------------------
__global__ __launch_bounds__(256, 4) void sinkhorn_loop(
    const _Float16* __restrict__ C, const _Float16* __restrict__ CT,
    float* __restrict__ u, float* __restrict__ v,
    float* __restrict__ err,     // [MAX_ITER][16] per-batch |du| bins
    int* __restrict__ gcnt,      // [MAX_ITER] arrival counters
    int* __restrict__ bar)       // [16][2] (cnt, gen) per batch
{
    __shared__ float ldsvk[1024];
    __shared__ float red[4];
    __shared__ int s_flag;
    const int tid = threadIdx.x, wave = tid >> 6, lane = tid & 63;
    const int b = blockIdx.x >> 6, l = blockIdx.x & 63;

    const _Float16* Cb  = C  + ((size_t)b << 20);
    const _Float16* CTb = CT + ((size_t)b << 20);
    float* ub = u + (b << 10);
    float* vb = v + (b << 10);
    int* cntp = bar + (b << 1);
    int* genp = bar + (b << 1) + 1;

    const int rbase = (l << 4) + (wave << 1);
    int flag = 0;

    for (int it = 0; it < MAX_ITER; ++it) {
        // ---------- U half-step: u <- f(C, v) ----------
        {   float4 t = ((const float4*)vb)[tid];
            t.x *= K2; t.y *= K2; t.z *= K2; t.w *= K2;
            ((float4*)ldsvk)[tid] = t;
        }
        __syncthreads();
        float werr = 0.f;
#pragma unroll 1
        for (int c = 0; c < 2; ++c)        // unroll 1: keep VGPR <= 128
            werr += half_step(Cb, ldsvk, ub, rbase + (c << 3), lane, 1);
        if (lane == 0) red[wave] = werr;
        __syncthreads();
        if (tid == 0) {
            atomicAdd(err + (it << 4) + b, red[0] + red[1] + red[2] + red[3]);
            __threadfence();
            __hip_atomic_fetch_add(gcnt + it, 1, __ATOMIC_RELEASE, __HIP_MEMORY_SCOPE_AGENT);
        }
        batch_barrier(cntp, genp, tid);    // u[b] complete + visible

        // ---------- V half-step: v <- f(CT, u) ----------
        {   float4 t = ((const float4*)ub)[tid];
            t.x *= K2; t.y *= K2; t.z *= K2; t.w *= K2;
            ((float4*)ldsvk)[tid] = t;
        }
        __syncthreads();
#pragma unroll 1
        for (int c = 0; c < 2; ++c)
            half_step(CTb, ldsvk, vb, rbase + (c << 3), lane, 0);
        batch_barrier(cntp, genp, tid);    // v[b] complete + visible

        // ---------- done flag gating iteration it+1 (same chain as before:
        // dflag[it+1] = dflag[it] | (sum_b err[b][it] < 16*0.1)) ----------
        if (tid == 0) {
            while (__hip_atomic_load(gcnt + it, __ATOMIC_ACQUIRE, __HIP_MEMORY_SCOPE_AGENT) < 1024)
                __builtin_amdgcn_s_sleep(8);
            float e = 0.f;
            const float* ep = err + (it << 4);
#pragma unroll
            for (int bb = 0; bb < 16; ++bb) e += ep[bb];
            s_flag = flag | (e < 1.6f ? 1 : 0);
        }
        __syncthreads();
        flag = s_flag;
        if (flag) break;   // frozen: u,v keep their converged values
    }
}

// ---------------------------------------------------------------------------
// cost = mean_b sum_ij exp((u_i + v_j - C_ij)/eps) * C_ij   (unchanged)
// ---------------------------------------------------------------------------
__global__ __launch_bounds__(256) void cost_kernel(
    const _Float16* __restrict__ C, const float* __restrict__ u,
    const float* __restrict__ v, float* __restrict__ out)
{
    __shared__ float ldsv[1024];
    __shared__ float red[4];
    const int tid = threadIdx.x, wave = tid >> 6, lane = tid & 63;
    const int b = blockIdx.x >> 5, l = blockIdx.x & 31;

    ((float4*)ldsv)[tid] = ((const float4*)(v + (b << 10)))[tid];
    __syncthreads();

    const _Float16* Cb = C + ((size_t)b << 20);
    const float* ub = u + (b << 10);
    const float4* V4 = (const float4*)ldsv;
    float csum = 0.f;
    for (int rr = 0; rr < 8; ++rr) {
        const int row = (l << 5) + (wave << 3) + rr;
        const float ui = ub[row];
        const half8* Crow = (const half8*)(Cb + (size_t)row * NN);
#pragma unroll
        for (int k = 0; k < 2; ++k) {
            const int m = lane + (k << 6);
            half8 c8 = Crow[m];
            float4 va = V4[2 * m];
            float4 vb = V4[2 * m + 1];
            float vv[8] = {va.x, va.y, va.z, va.w, vb.x, vb.y, vb.z, vb.w};
#pragma unroll
            for (int j = 0; j < 8; ++j) {
                float c = (float)c8[j];
                csum += EXP2F((ui + vv[j] - c) * K2) * c;
            }
        }
    }
#pragma unroll
    for (int off = 32; off > 0; off >>= 1) csum += __shfl_xor(csum, off);
    if (lane == 0) red[wave] = csum;
    __syncthreads();
    if (tid == 0)
        atomicAdd(out, (red[0] + red[1] + red[2] + red[3]) * (1.0f / 16.0f));
}

extern "C" void kernel_launch(void* const* d_in, const int* in_sizes, int n_in,
                              void* d_out, int out_size, void* d_ws, size_t ws_size,
                              hipStream_t stream) {
    const float* x = (const float*)d_in[0];  // output: [16,1024,32] fp32
    const float* y = (const float*)d_in[1];  // labels: [16,1024,32] fp32

    char* wsb = (char*)d_ws;
    _Float16* C  = (_Float16*)wsb;                   // 16 M halves (32 MB)
    _Float16* CT = (_Float16*)(wsb + 33554432);      // 16 M halves (32 MB)
    float* u     = (float*)(wsb + 67108864);         // 16384
    float* v     = u + 16384;                        // 16384
    float* err   = v + 16384;                        // [100][16] (2048 slot)
    int*   gcnt  = (int*)(err + 2048);               // 128
    int*   bar   = gcnt + 128;                       // 64
    float* out   = (float*)d_out;

    // u, v, err, gcnt, bar contiguous — zero them (+ out) every call
    (void)hipMemsetAsync(u, 0, (size_t)(2 * 16384 + 2048 + 128 + 64) * 4, stream);
    (void)hipMemsetAsync(out, 0, sizeof(float), stream);

    build_dist<<<dim3(16 * 64), dim3(256), 0, stream>>>(x, y, C);
    build_dist<<<dim3(16 * 64), dim3(256), 0, stream>>>(y, x, CT);

    // one persistent launch replaces 200 lse_pass dispatches
    sinkhorn_loop<<<dim3(1024), dim3(256), 0, stream>>>(C, CT, u, v, err, gcnt, bar);

    cost_kernel<<<dim3(512), dim3(256), 0, stream>>>(C, u, v, out);
}

// Round 2
// 2971.497 us; speedup vs baseline: 12.0609x; 12.0609x over previous
//
#include <hip/hip_runtime.h>

// Problem constants (B=16, N=M=1024, D=32)
constexpr int   NN       = 1024;
constexpr float EPSf     = 1e-3f;
constexpr int   MAX_ITER = 100;

// exp2-domain scale: x = (v - C) * (1/eps) * log2(e)
#define K2        1442.6950408889634f
#define LN2f      0.6931471805599453f
#define INV_LN2   1.4426950408889634f
#define INV_EPS   1000.0f
#define LOGK      (-6.9314616f)   // log(1/1024 + 1e-8)
#define NEG_LOGK2 9.9999852f      // -LOGK * INV_LN2  (= -log2(1/1024+1e-8))

// hardware transcendentals (avoid libm name collisions)
#define EXP2F(x) __builtin_amdgcn_exp2f(x)   // 2^x
#define LOG2F(x) __builtin_amdgcn_logf(x)    // log2(x)

typedef _Float16 half8 __attribute__((ext_vector_type(8)));

// ---------------------------------------------------------------------------
// dist[b][p][q] = sum_d (A[b][p][d] - Bm[b][q][d])^2, stored fp16. (unchanged)
// Only C is needed now — the v-pass no longer reads CT.
// ---------------------------------------------------------------------------
__global__ __launch_bounds__(256) void build_dist(
    const float* __restrict__ A, const float* __restrict__ Bm,
    _Float16* __restrict__ out)
{
    __shared__ float aLds[16 * 32];
    __shared__ float bLds[256 * 33];
    const int b  = blockIdx.x >> 6;       // 16 * 64 blocks
    const int pt = blockIdx.x & 63;
    const int t  = threadIdx.x;

    const float* Ab = A  + ((size_t)b * NN + pt * 16) * 32;
    const float* Bb = Bm + (size_t)b * NN * 32;

    if (t < 128) ((float4*)aLds)[t] = ((const float4*)Ab)[t];

    for (int qt = 0; qt < 4; ++qt) {
        __syncthreads();
        const float4* src = (const float4*)(Bb + qt * 256 * 32);
#pragma unroll
        for (int i = 0; i < 8; ++i) {
            int j = t + (i << 8);
            float4 val = src[j];
            int q = j >> 3, dd = (j & 7) << 2;
            float* dst = &bLds[q * 33 + dd];
            dst[0] = val.x; dst[1] = val.y; dst[2] = val.z; dst[3] = val.w;
        }
        __syncthreads();

        float br[32];
#pragma unroll
        for (int d = 0; d < 32; ++d) br[d] = bLds[t * 33 + d];

#pragma unroll
        for (int p = 0; p < 16; ++p) {
            float acc = 0.f;
#pragma unroll
            for (int d4 = 0; d4 < 8; ++d4) {
                float4 a4 = ((const float4*)(aLds + p * 32))[d4];
                float dx = a4.x - br[d4 * 4 + 0];
                float dy = a4.y - br[d4 * 4 + 1];
                float dz = a4.z - br[d4 * 4 + 2];
                float dw = a4.w - br[d4 * 4 + 3];
                acc += dx * dx + dy * dy + dz * dz + dw * dw;
            }
            out[((size_t)b * NN + pt * 16 + p) * NN + qt * 256 + t] = (_Float16)acc;
        }
    }
}

// ---------------------------------------------------------------------------
// Fused u-pass: updates u (bit-identical math to the old lse_pass u-step,
// incl. fast M-shifted path + max-shifted fallback) AND emits per-column
// streaming-LSE partials for the v-update:
//   arg_ij = x0_ij + u'_i*K2 - LOGK2   ( = old v-pass's  x_v - Mv )
//   per block: Sm[b][l][j] = max_i arg, Ss[b][l][j] = sum_i exp2(arg - Sm)
// Grid 16*64 blocks, 256 threads; block owns 16 rows (4 waves x 2 rows x
// 2 serial chunks). LDS: 4KB vk + 2x16KB column reduce = ~36.2 KB -> 4/CU.
// ---------------------------------------------------------------------------
__global__ __launch_bounds__(256, 4) void u_pass_fused(
    const _Float16* __restrict__ Cmat,
    const float* __restrict__ vvec,   // v_old
    float* __restrict__ uvec,         // u (updated in place)
    float* __restrict__ Sm, float* __restrict__ Ss,   // [16][64][1024]
    float* __restrict__ err,          // err[16][128] (old layout)
    const int* __restrict__ dflag, int it)
{
    __shared__ float ldsvk[1024];
    __shared__ float redm[4][1024];
    __shared__ float reds[4][1024];
    __shared__ float redw[4];
    __shared__ int s_done;
    const int tid = threadIdx.x, wave = tid >> 6, lane = tid & 63;
    const int b = blockIdx.x >> 6, l = blockIdx.x & 63;

    if (tid == 0) s_done = dflag[it];
    {   // stage vk = v_old * K2
        float4 t = ((const float4*)(vvec + (b << 10)))[tid];
        t.x *= K2; t.y *= K2; t.z *= K2; t.w *= K2;
        ((float4*)ldsvk)[tid] = t;
    }
    __syncthreads();
    if (s_done) return;   // frozen: u,v keep their converged values

    const _Float16* Cb = Cmat + ((size_t)b << 20);
    float* ub = uvec + (b << 10);
    const float4* V4 = (const float4*)ldsvk;

    float cm[16], cs[16];
    float werr = 0.f;

#pragma unroll 1
    for (int ch = 0; ch < 2; ++ch) {
        const int r = (l << 4) + (ch << 3) + (wave << 1);
        const half8* r0 = (const half8*)(Cb + (size_t)r * NN);
        const half8* r1 = (const half8*)(Cb + (size_t)(r + 1) * NN);

        const float uo0 = ub[r], uo1 = ub[r + 1];
        const float M0 = (LOGK - uo0 * INV_EPS) * INV_LN2;
        const float M1 = (LOGK - uo1 * INV_EPS) * INV_LN2;

        float x0[16], x1[16];
#pragma unroll
        for (int k = 0; k < 2; ++k) {
            const int m_ = lane + (k << 6);
            half8 c0 = r0[m_];
            half8 c1 = r1[m_];
            float4 va = V4[2 * m_], vb = V4[2 * m_ + 1];
            float vv[8] = {va.x, va.y, va.z, va.w, vb.x, vb.y, vb.z, vb.w};
#pragma unroll
            for (int j = 0; j < 8; ++j) {
                x0[8 * k + j] = fmaf((float)c0[j], -K2, vv[j]);
                x1[8 * k + j] = fmaf((float)c1[j], -K2, vv[j]);
            }
        }
        float s0 = 0.f, s1 = 0.f;
#pragma unroll
        for (int i = 0; i < 16; ++i) {
            s0 += EXP2F(x0[i] - M0);
            s1 += EXP2F(x1[i] - M1);
        }
#pragma unroll
        for (int off = 32; off > 0; off >>= 1) {
            s0 += __shfl_xor(s0, off);
            s1 += __shfl_xor(s1, off);
        }

        float lse2_0, lse2_1;
        if (__builtin_expect(!(s0 >= 1e-27f && s0 <= 1e38f) ||
                             !(s1 >= 1e-27f && s1 <= 1e38f), 0)) {
            // fallback: classic max-shifted LSE (fires at it=0 and on drift)
            float m0 = x0[0], m1 = x1[0];
#pragma unroll
            for (int i = 1; i < 16; ++i) { m0 = fmaxf(m0, x0[i]); m1 = fmaxf(m1, x1[i]); }
#pragma unroll
            for (int off = 32; off > 0; off >>= 1) {
                m0 = fmaxf(m0, __shfl_xor(m0, off));
                m1 = fmaxf(m1, __shfl_xor(m1, off));
            }
            float t0 = 0.f, t1 = 0.f;
#pragma unroll
            for (int i = 0; i < 16; ++i) { t0 += EXP2F(x0[i] - m0); t1 += EXP2F(x1[i] - m1); }
#pragma unroll
            for (int off = 32; off > 0; off >>= 1) {
                t0 += __shfl_xor(t0, off);
                t1 += __shfl_xor(t1, off);
            }
            lse2_0 = m0 + LOG2F(t0);
            lse2_1 = m1 + LOG2F(t1);
        } else {
            lse2_0 = M0 + LOG2F(s0);
            lse2_1 = M1 + LOG2F(s1);
        }

        // all lanes know the wave-uniform sums -> all compute u' locally
        const float n0 = EPSf * (LOGK - lse2_0 * LN2f);
        const float n1 = EPSf * (LOGK - lse2_1 * LN2f);
        if (lane == 0) {
            werr += fabsf(n0 - uo0) + fabsf(n1 - uo1);
            ub[r]     = n0;
            ub[r + 1] = n1;
        }

        // ---- v-direction column partials:  arg = x + (u'*K2 - LOGK2) ----
        const float A0 = fmaf(n0, K2, NEG_LOGK2);
        const float A1 = fmaf(n1, K2, NEG_LOGK2);
#pragma unroll
        for (int i = 0; i < 16; ++i) {
            const float a0 = x0[i] + A0;
            const float a1 = x1[i] + A1;
            const float mx = fmaxf(a0, a1);
            const float sv = EXP2F(a0 - mx) + EXP2F(a1 - mx);
            if (ch == 0) { cm[i] = mx; cs[i] = sv; }
            else {
                const float m2 = fmaxf(cm[i], mx);
                cs[i] = fmaf(cs[i], EXP2F(cm[i] - m2), sv * EXP2F(mx - m2));
                cm[i] = m2;
            }
        }
    }

    // ---- cross-wave per-column (m,s) reduce through LDS ----
    if (lane == 0) redw[wave] = werr;
#pragma unroll
    for (int k = 0; k < 2; ++k) {
        const int cbase = (lane + (k << 6)) << 3;   // columns 8*m_ .. 8*m_+7
        *(float4*)&redm[wave][cbase]     = make_float4(cm[8*k+0], cm[8*k+1], cm[8*k+2], cm[8*k+3]);
        *(float4*)&redm[wave][cbase + 4] = make_float4(cm[8*k+4], cm[8*k+5], cm[8*k+6], cm[8*k+7]);
        *(float4*)&reds[wave][cbase]     = make_float4(cs[8*k+0], cs[8*k+1], cs[8*k+2], cs[8*k+3]);
        *(float4*)&reds[wave][cbase + 4] = make_float4(cs[8*k+4], cs[8*k+5], cs[8*k+6], cs[8*k+7]);
    }
    __syncthreads();

    if (tid == 0)
        atomicAdd(err + (b << 7) + it, redw[0] + redw[1] + redw[2] + redw[3]);

    {   // each thread folds 4 columns across the 4 waves and writes Sm/Ss
        const int c = tid << 2;
        float4 m0 = *(const float4*)&redm[0][c];
        float4 m1 = *(const float4*)&redm[1][c];
        float4 m2 = *(const float4*)&redm[2][c];
        float4 m3 = *(const float4*)&redm[3][c];
        float4 s0 = *(const float4*)&reds[0][c];
        float4 s1 = *(const float4*)&reds[1][c];
        float4 s2 = *(const float4*)&reds[2][c];
        float4 s3 = *(const float4*)&reds[3][c];
        float4 M, S;
        M.x = fmaxf(fmaxf(m0.x, m1.x), fmaxf(m2.x, m3.x));
        M.y = fmaxf(fmaxf(m0.y, m1.y), fmaxf(m2.y, m3.y));
        M.z = fmaxf(fmaxf(m0.z, m1.z), fmaxf(m2.z, m3.z));
        M.w = fmaxf(fmaxf(m0.w, m1.w), fmaxf(m2.w, m3.w));
        S.x = s0.x*EXP2F(m0.x-M.x) + s1.x*EXP2F(m1.x-M.x) + s2.x*EXP2F(m2.x-M.x) + s3.x*EXP2F(m3.x-M.x);
        S.y = s0.y*EXP2F(m0.y-M.y) + s1.y*EXP2F(m1.y-M.y) + s2.y*EXP2F(m2.y-M.y) + s3.y*EXP2F(m3.y-M.y);
        S.z = s0.z*EXP2F(m0.z-M.z) + s1.z*EXP2F(m1.z-M.z) + s2.z*EXP2F(m2.z-M.z) + s3.z*EXP2F(m3.z-M.z);
        S.w = s0.w*EXP2F(m0.w-M.w) + s1.w*EXP2F(m1.w-M.w) + s2.w*EXP2F(m2.w-M.w) + s3.w*EXP2F(m3.w-M.w);
        float* smb = Sm + ((size_t)blockIdx.x << 10) + c;
        float* ssb = Ss + ((size_t)blockIdx.x << 10) + c;
        *(float4*)smb = M;
        *(float4*)ssb = S;
    }
}

// ---------------------------------------------------------------------------
// v-finish: combine the 64 per-block (m,s) partials per column.
//   lse2(args_j) = m* + log2(sum_l s_l * 2^(m_l - m*))
//   v'_j = v_j - EPS*LN2*lse2(args_j)        (v_j cancellation identity)
// Also maintains the freeze chain (block 0), exactly as the old v-pass did.
// Grid 64 x 256: block (b=blk>>2, quarter q), thread owns column q*256+tid.
// ---------------------------------------------------------------------------
__global__ __launch_bounds__(256) void v_finish(
    const float* __restrict__ Sm, const float* __restrict__ Ss,
    float* __restrict__ vvec, const float* __restrict__ err,
    int* __restrict__ dflag, int it)
{
    __shared__ int s_done;
    const int tid = threadIdx.x;
    const int b = blockIdx.x >> 2, q = blockIdx.x & 3;

    // freeze chain: dflag[it+1] = dflag[it] | (sum_b err[b][it] < 1.6)
    if (blockIdx.x == 0 && tid < 16) {
        float e = err[(tid << 7) + it];
        e += __shfl_xor(e, 1); e += __shfl_xor(e, 2);
        e += __shfl_xor(e, 4); e += __shfl_xor(e, 8);
        if (tid == 0) dflag[it + 1] = dflag[it] | (e < 1.6f ? 1 : 0);
    }
    if (tid == 0) s_done = dflag[it];
    __syncthreads();
    if (s_done) return;

    const int j = (q << 8) + tid;
    const float* smb = Sm + ((size_t)b << 16) + j;
    const float* ssb = Ss + ((size_t)b << 16) + j;

    float mstar = -3.4e38f;
#pragma unroll 8
    for (int l = 0; l < 64; ++l) mstar = fmaxf(mstar, smb[l << 10]);
    float T = 0.f;
#pragma unroll 8
    for (int l = 0; l < 64; ++l) T += ssb[l << 10] * EXP2F(smb[l << 10] - mstar);

    const float l2a = mstar + LOG2F(T);          // lse2 of all args
    vvec[(b << 10) + j] -= EPSf * LN2f * l2a;    // v' = v - eps*ln2*lse2
}

// ---------------------------------------------------------------------------
// cost = mean_b sum_ij exp((u_i + v_j - C_ij)/eps) * C_ij   (unchanged)
// ---------------------------------------------------------------------------
__global__ __launch_bounds__(256) void cost_kernel(
    const _Float16* __restrict__ C, const float* __restrict__ u,
    const float* __restrict__ v, float* __restrict__ out)
{
    __shared__ float ldsv[1024];
    __shared__ float red[4];
    const int tid = threadIdx.x, wave = tid >> 6, lane = tid & 63;
    const int b = blockIdx.x >> 5, l = blockIdx.x & 31;

    ((float4*)ldsv)[tid] = ((const float4*)(v + (b << 10)))[tid];
    __syncthreads();

    const _Float16* Cb = C + ((size_t)b << 20);
    const float* ub = u + (b << 10);
    const float4* V4 = (const float4*)ldsv;
    float csum = 0.f;
    for (int rr = 0; rr < 8; ++rr) {
        const int row = (l << 5) + (wave << 3) + rr;
        const float ui = ub[row];
        const half8* Crow = (const half8*)(Cb + (size_t)row * NN);
#pragma unroll
        for (int k = 0; k < 2; ++k) {
            const int m = lane + (k << 6);
            half8 c8 = Crow[m];
            float4 va = V4[2 * m];
            float4 vb = V4[2 * m + 1];
            float vv[8] = {va.x, va.y, va.z, va.w, vb.x, vb.y, vb.z, vb.w};
#pragma unroll
            for (int j = 0; j < 8; ++j) {
                float c = (float)c8[j];
                csum += EXP2F((ui + vv[j] - c) * K2) * c;
            }
        }
    }
#pragma unroll
    for (int off = 32; off > 0; off >>= 1) csum += __shfl_xor(csum, off);
    if (lane == 0) red[wave] = csum;
    __syncthreads();
    if (tid == 0)
        atomicAdd(out, (red[0] + red[1] + red[2] + red[3]) * (1.0f / 16.0f));
}

extern "C" void kernel_launch(void* const* d_in, const int* in_sizes, int n_in,
                              void* d_out, int out_size, void* d_ws, size_t ws_size,
                              hipStream_t stream) {
    const float* x = (const float*)d_in[0];  // output: [16,1024,32] fp32
    const float* y = (const float*)d_in[1];  // labels: [16,1024,32] fp32

    char* wsb = (char*)d_ws;
    _Float16* C  = (_Float16*)wsb;                       // 32 MB
    float* Sm    = (float*)(wsb + (32u << 20));          // 4 MB  [16][64][1024]
    float* Ss    = (float*)(wsb + (36u << 20));          // 4 MB
    float* u     = (float*)(wsb + (40u << 20));          // 16384 floats
    float* v     = u + 16384;                            // 16384 floats
    float* err   = v + 16384;                            // [16][128]
    int*   dflag = (int*)(err + 2048);                   // 128
    float* out   = (float*)d_out;

    // u, v, err, dflag contiguous — zero them (+ out) every call
    (void)hipMemsetAsync(u, 0, (size_t)(2 * 16384 + 2048 + 128) * 4, stream);
    (void)hipMemsetAsync(out, 0, sizeof(float), stream);

    build_dist<<<dim3(16 * 64), dim3(256), 0, stream>>>(x, y, C);   // CT no longer needed

    for (int it = 0; it < MAX_ITER; ++it) {
        u_pass_fused<<<dim3(1024), dim3(256), 0, stream>>>(C, v, u, Sm, Ss, err, dflag, it);
        v_finish<<<dim3(64), dim3(256), 0, stream>>>(Sm, Ss, v, err, dflag, it);
    }

    cost_kernel<<<dim3(512), dim3(256), 0, stream>>>(C, u, v, out);
}

// Round 3
// 1971.869 us; speedup vs baseline: 18.1751x; 1.5069x over previous
//
#include <hip/hip_runtime.h>

// Problem constants (B=16, N=M=1024, D=32)
constexpr int   NN       = 1024;
constexpr float EPSf     = 1e-3f;
constexpr int   MAX_ITER = 100;

// exp2-domain scale: x = (v - C) * (1/eps) * log2(e)
#define K2        1442.6950408889634f
#define LN2f      0.6931471805599453f
#define INV_LN2   1.4426950408889634f
#define INV_EPS   1000.0f
#define LOGK      (-6.9314616f)   // log(1/1024 + 1e-8)
#define NEG_LOGK2 9.9999852f      // -LOGK * INV_LN2

// hardware transcendentals (avoid libm name collisions)
#define EXP2F(x) __builtin_amdgcn_exp2f(x)   // 2^x
#define LOG2F(x) __builtin_amdgcn_logf(x)    // log2(x)

typedef _Float16 half8 __attribute__((ext_vector_type(8)));

// ---------------------------------------------------------------------------
// dist[b][p][q] = sum_d (A[b][p][d] - Bm[b][q][d])^2, stored fp16. (unchanged)
// ---------------------------------------------------------------------------
__global__ __launch_bounds__(256) void build_dist(
    const float* __restrict__ A, const float* __restrict__ Bm,
    _Float16* __restrict__ out)
{
    __shared__ float aLds[16 * 32];
    __shared__ float bLds[256 * 33];
    const int b  = blockIdx.x >> 6;       // 16 * 64 blocks
    const int pt = blockIdx.x & 63;
    const int t  = threadIdx.x;

    const float* Ab = A  + ((size_t)b * NN + pt * 16) * 32;
    const float* Bb = Bm + (size_t)b * NN * 32;

    if (t < 128) ((float4*)aLds)[t] = ((const float4*)Ab)[t];

    for (int qt = 0; qt < 4; ++qt) {
        __syncthreads();
        const float4* src = (const float4*)(Bb + qt * 256 * 32);
#pragma unroll
        for (int i = 0; i < 8; ++i) {
            int j = t + (i << 8);
            float4 val = src[j];
            int q = j >> 3, dd = (j & 7) << 2;
            float* dst = &bLds[q * 33 + dd];
            dst[0] = val.x; dst[1] = val.y; dst[2] = val.z; dst[3] = val.w;
        }
        __syncthreads();

        float br[32];
#pragma unroll
        for (int d = 0; d < 32; ++d) br[d] = bLds[t * 33 + d];

#pragma unroll
        for (int p = 0; p < 16; ++p) {
            float acc = 0.f;
#pragma unroll
            for (int d4 = 0; d4 < 8; ++d4) {
                float4 a4 = ((const float4*)(aLds + p * 32))[d4];
                float dx = a4.x - br[d4 * 4 + 0];
                float dy = a4.y - br[d4 * 4 + 1];
                float dz = a4.z - br[d4 * 4 + 2];
                float dw = a4.w - br[d4 * 4 + 3];
                acc += dx * dx + dy * dy + dz * dz + dw * dw;
            }
            out[((size_t)b * NN + pt * 16 + p) * NN + qt * 256 + t] = (_Float16)acc;
        }
    }
}

// (m,s) streaming-LSE merge: (ma,sa) <- (ma,sa) (+) (mb,sb)
__device__ __forceinline__ void msmerge(float& ma, float& sa, float mb, float sb)
{
    const float m2 = fmaxf(ma, mb);
    sa = fmaf(sa, EXP2F(ma - m2), sb * EXP2F(mb - m2));
    ma = m2;
}

// ---------------------------------------------------------------------------
// Fused u-pass: grid 2048 (= 16 batches x 128 row-blocks), 8 rows/block,
// 2 rows/wave — identical per-thread shape to the proven 8.5 µs lse_pass.
// Updates u (bit-identical fast/fallback LSE), then transforms the x arrays
// IN PLACE into per-column (m,s) partials (no extra live arrays), folds the
// 4 waves via a two-stage 16 KB LDS scheme (v-staging buffer aliased over
// the fold buffer), and writes one block partial per column:
//   Sm/Ss[b*128 + l][1024]  (8 MB each)
// ---------------------------------------------------------------------------
__global__ __launch_bounds__(256) void u_pass_fused(
    const _Float16* __restrict__ Cmat,
    const float* __restrict__ vvec,   // v_old
    float* __restrict__ uvec,         // u (updated in place)
    float* __restrict__ Sm, float* __restrict__ Ss,   // [2048][1024]
    float* __restrict__ err,          // err[16][128]
    const int* __restrict__ dflag, int it)
{
    __shared__ float redm[2][1024];   // slot arrays; redm[0] doubles as vk stage
    __shared__ float reds[2][1024];
    __shared__ float redw[4];
    __shared__ int s_done;
    float* ldsvk = &redm[0][0];

    const int tid = threadIdx.x, wave = tid >> 6, lane = tid & 63;
    const int b = blockIdx.x >> 7, l = blockIdx.x & 127;

    if (tid == 0) s_done = dflag[it];
    {   // stage vk = v_old * K2 into redm[0] (dead after x-build)
        float4 t = ((const float4*)(vvec + (b << 10)))[tid];
        t.x *= K2; t.y *= K2; t.z *= K2; t.w *= K2;
        ((float4*)ldsvk)[tid] = t;
    }
    __syncthreads();
    if (s_done) return;   // frozen: u,v keep their converged values

    const _Float16* Cb = Cmat + ((size_t)b << 20);
    float* ub = uvec + (b << 10);
    const float4* V4 = (const float4*)ldsvk;

    const int r = (l << 3) + (wave << 1);
    const half8* r0 = (const half8*)(Cb + (size_t)r * NN);
    const half8* r1 = (const half8*)(Cb + (size_t)(r + 1) * NN);

    const float uo0 = ub[r], uo1 = ub[r + 1];
    const float M0 = (LOGK - uo0 * INV_EPS) * INV_LN2;
    const float M1 = (LOGK - uo1 * INV_EPS) * INV_LN2;

    float x0[16], x1[16];
#pragma unroll
    for (int k = 0; k < 2; ++k) {
        const int m_ = lane + (k << 6);
        half8 c0 = r0[m_];
        half8 c1 = r1[m_];
        float4 va = V4[2 * m_], vb = V4[2 * m_ + 1];
        float vv[8] = {va.x, va.y, va.z, va.w, vb.x, vb.y, vb.z, vb.w};
#pragma unroll
        for (int j = 0; j < 8; ++j) {
            x0[8 * k + j] = fmaf((float)c0[j], -K2, vv[j]);
            x1[8 * k + j] = fmaf((float)c1[j], -K2, vv[j]);
        }
    }
    float s0 = 0.f, s1 = 0.f;
#pragma unroll
    for (int i = 0; i < 16; ++i) {
        s0 += EXP2F(x0[i] - M0);
        s1 += EXP2F(x1[i] - M1);
    }
#pragma unroll
    for (int off = 32; off > 0; off >>= 1) {
        s0 += __shfl_xor(s0, off);
        s1 += __shfl_xor(s1, off);
    }

    float lse2_0, lse2_1;
    if (__builtin_expect(!(s0 >= 1e-27f && s0 <= 1e38f) ||
                         !(s1 >= 1e-27f && s1 <= 1e38f), 0)) {
        // fallback: classic max-shifted LSE (fires at it=0 and on drift)
        float m0 = x0[0], m1 = x1[0];
#pragma unroll
        for (int i = 1; i < 16; ++i) { m0 = fmaxf(m0, x0[i]); m1 = fmaxf(m1, x1[i]); }
#pragma unroll
        for (int off = 32; off > 0; off >>= 1) {
            m0 = fmaxf(m0, __shfl_xor(m0, off));
            m1 = fmaxf(m1, __shfl_xor(m1, off));
        }
        float t0 = 0.f, t1 = 0.f;
#pragma unroll
        for (int i = 0; i < 16; ++i) { t0 += EXP2F(x0[i] - m0); t1 += EXP2F(x1[i] - m1); }
#pragma unroll
        for (int off = 32; off > 0; off >>= 1) {
            t0 += __shfl_xor(t0, off);
            t1 += __shfl_xor(t1, off);
        }
        lse2_0 = m0 + LOG2F(t0);
        lse2_1 = m1 + LOG2F(t1);
    } else {
        lse2_0 = M0 + LOG2F(s0);
        lse2_1 = M1 + LOG2F(s1);
    }

    // all lanes know the wave-uniform sums -> all compute u' locally
    const float n0 = EPSf * (LOGK - lse2_0 * LN2f);
    const float n1 = EPSf * (LOGK - lse2_1 * LN2f);
    float werr = 0.f;
    if (lane == 0) {
        werr = fabsf(n0 - uo0) + fabsf(n1 - uo1);
        ub[r]     = n0;
        ub[r + 1] = n1;
        redw[wave] = werr;
    }

    // ---- transform x arrays IN PLACE into 2-row (m,s) column partials ----
    //   arg = x + (u'*K2 - LOGK2);  x0[i] <- m, x1[i] <- s
    const float A0 = fmaf(n0, K2, NEG_LOGK2);
    const float A1 = fmaf(n1, K2, NEG_LOGK2);
#pragma unroll
    for (int i = 0; i < 16; ++i) {
        const float a0 = x0[i] + A0;
        const float a1 = x1[i] + A1;
        const float mx = fmaxf(a0, a1);
        x1[i] = EXP2F(a0 - mx) + EXP2F(a1 - mx);
        x0[i] = mx;
    }

    __syncthreads();   // vk (redm[0]) dead; redw complete

    if (tid == 0)
        atomicAdd(err + (b << 7) + it, redw[0] + redw[1] + redw[2] + redw[3]);

    // stage 1: waves 0,1 deposit their (m,s) per column
    if (wave < 2) {
#pragma unroll
        for (int k = 0; k < 2; ++k) {
            const int base = (lane + (k << 6)) << 3;
            *(float4*)&redm[wave][base]     = make_float4(x0[8*k+0], x0[8*k+1], x0[8*k+2], x0[8*k+3]);
            *(float4*)&redm[wave][base + 4] = make_float4(x0[8*k+4], x0[8*k+5], x0[8*k+6], x0[8*k+7]);
            *(float4*)&reds[wave][base]     = make_float4(x1[8*k+0], x1[8*k+1], x1[8*k+2], x1[8*k+3]);
            *(float4*)&reds[wave][base + 4] = make_float4(x1[8*k+4], x1[8*k+5], x1[8*k+6], x1[8*k+7]);
        }
    }
    __syncthreads();

    // stage 2: waves 2,3 merge into slots 0,1
    if (wave >= 2) {
        const int w = wave - 2;
#pragma unroll
        for (int k = 0; k < 2; ++k) {
            const int base = (lane + (k << 6)) << 3;
#pragma unroll
            for (int h = 0; h < 2; ++h) {
                float4 ma = *(const float4*)&redm[w][base + 4*h];
                float4 sa = *(const float4*)&reds[w][base + 4*h];
                float mr[4] = {ma.x, ma.y, ma.z, ma.w};
                float sr[4] = {sa.x, sa.y, sa.z, sa.w};
#pragma unroll
                for (int j = 0; j < 4; ++j)
                    msmerge(mr[j], sr[j], x0[8*k + 4*h + j], x1[8*k + 4*h + j]);
                *(float4*)&redm[w][base + 4*h] = make_float4(mr[0], mr[1], mr[2], mr[3]);
                *(float4*)&reds[w][base + 4*h] = make_float4(sr[0], sr[1], sr[2], sr[3]);
            }
        }
    }
    __syncthreads();

    // final fold of 2 slots -> block partial, write to global
    {
        const int c = tid << 2;
        float4 m0 = *(const float4*)&redm[0][c];
        float4 m1 = *(const float4*)&redm[1][c];
        float4 sA = *(const float4*)&reds[0][c];
        float4 sB = *(const float4*)&reds[1][c];
        float mr[4] = {m0.x, m0.y, m0.z, m0.w};
        float sr[4] = {sA.x, sA.y, sA.z, sA.w};
        float mb[4] = {m1.x, m1.y, m1.z, m1.w};
        float sb[4] = {sB.x, sB.y, sB.z, sB.w};
#pragma unroll
        for (int j = 0; j < 4; ++j) msmerge(mr[j], sr[j], mb[j], sb[j]);
        *(float4*)(Sm + ((size_t)blockIdx.x << 10) + c) = make_float4(mr[0], mr[1], mr[2], mr[3]);
        *(float4*)(Ss + ((size_t)blockIdx.x << 10) + c) = make_float4(sr[0], sr[1], sr[2], sr[3]);
    }
}

// ---------------------------------------------------------------------------
// v-finish: fold the 128 per-block (m,s) partials per column, then
//   v'_j = v_j - EPS*LN2*lse2(args_j)  ==  EPS*(LOGK - LN2*lse2_col)
// Grid 256 = 16 batches x 16 col-groups of 64. Thread (c=tid&63, g=tid>>6)
// folds partial rows l = g*32..g*32+31 with 4 independent accumulators
// (MLP), then a 2 KB LDS fold across g. Chain update in block 0 (as before).
// ---------------------------------------------------------------------------
__global__ __launch_bounds__(256) void v_finish(
    const float* __restrict__ Sm, const float* __restrict__ Ss,
    float* __restrict__ vvec, const float* __restrict__ err,
    int* __restrict__ dflag, int it)
{
    __shared__ float fm[4][64], fs[4][64];
    __shared__ int s_done;
    const int tid = threadIdx.x;
    const int b = blockIdx.x >> 4, cg = blockIdx.x & 15;
    const int c = tid & 63, g = tid >> 6;
    const int col = (cg << 6) + c;

    // freeze chain: dflag[it+1] = dflag[it] | (sum_b err[b][it] < 1.6)
    if (blockIdx.x == 0 && tid < 16) {
        float e = err[(tid << 7) + it];
        e += __shfl_xor(e, 1); e += __shfl_xor(e, 2);
        e += __shfl_xor(e, 4); e += __shfl_xor(e, 8);
        if (tid == 0) dflag[it + 1] = dflag[it] | (e < 1.6f ? 1 : 0);
    }
    if (tid == 0) s_done = dflag[it];
    __syncthreads();
    if (s_done) return;

    const float* pm = Sm + (((size_t)b << 17)) + col;   // b*128 partial rows
    const float* ps = Ss + (((size_t)b << 17)) + col;
    const int l0 = g << 5;

    float M[4], S[4];
#pragma unroll
    for (int i = 0; i < 4; ++i) {
        M[i] = pm[(size_t)(l0 + i) << 10];
        S[i] = ps[(size_t)(l0 + i) << 10];
    }
#pragma unroll
    for (int j = 4; j < 32; j += 4) {
#pragma unroll
        for (int i = 0; i < 4; ++i) {
            const float m = pm[(size_t)(l0 + j + i) << 10];
            const float s = ps[(size_t)(l0 + j + i) << 10];
            msmerge(M[i], S[i], m, s);
        }
    }
    msmerge(M[0], S[0], M[1], S[1]);
    msmerge(M[2], S[2], M[3], S[3]);
    msmerge(M[0], S[0], M[2], S[2]);
    fm[g][c] = M[0];
    fs[g][c] = S[0];
    __syncthreads();

    if (tid < 64) {
        float Mf = fm[0][tid], Sf = fs[0][tid];
        msmerge(Mf, Sf, fm[1][tid], fs[1][tid]);
        msmerge(Mf, Sf, fm[2][tid], fs[2][tid]);
        msmerge(Mf, Sf, fm[3][tid], fs[3][tid]);
        const float l2a = Mf + LOG2F(Sf);
        vvec[(b << 10) + (cg << 6) + tid] -= EPSf * LN2f * l2a;
    }
}

// ---------------------------------------------------------------------------
// cost = mean_b sum_ij exp((u_i + v_j - C_ij)/eps) * C_ij   (unchanged)
// ---------------------------------------------------------------------------
__global__ __launch_bounds__(256) void cost_kernel(
    const _Float16* __restrict__ C, const float* __restrict__ u,
    const float* __restrict__ v, float* __restrict__ out)
{
    __shared__ float ldsv[1024];
    __shared__ float red[4];
    const int tid = threadIdx.x, wave = tid >> 6, lane = tid & 63;
    const int b = blockIdx.x >> 5, l = blockIdx.x & 31;

    ((float4*)ldsv)[tid] = ((const float4*)(v + (b << 10)))[tid];
    __syncthreads();

    const _Float16* Cb = C + ((size_t)b << 20);
    const float* ub = u + (b << 10);
    const float4* V4 = (const float4*)ldsv;
    float csum = 0.f;
    for (int rr = 0; rr < 8; ++rr) {
        const int row = (l << 5) + (wave << 3) + rr;
        const float ui = ub[row];
        const half8* Crow = (const half8*)(Cb + (size_t)row * NN);
#pragma unroll
        for (int k = 0; k < 2; ++k) {
            const int m = lane + (k << 6);
            half8 c8 = Crow[m];
            float4 va = V4[2 * m];
            float4 vb = V4[2 * m + 1];
            float vv[8] = {va.x, va.y, va.z, va.w, vb.x, vb.y, vb.z, vb.w};
#pragma unroll
            for (int j = 0; j < 8; ++j) {
                float c = (float)c8[j];
                csum += EXP2F((ui + vv[j] - c) * K2) * c;
            }
        }
    }
#pragma unroll
    for (int off = 32; off > 0; off >>= 1) csum += __shfl_xor(csum, off);
    if (lane == 0) red[wave] = csum;
    __syncthreads();
    if (tid == 0)
        atomicAdd(out, (red[0] + red[1] + red[2] + red[3]) * (1.0f / 16.0f));
}

extern "C" void kernel_launch(void* const* d_in, const int* in_sizes, int n_in,
                              void* d_out, int out_size, void* d_ws, size_t ws_size,
                              hipStream_t stream) {
    const float* x = (const float*)d_in[0];  // output: [16,1024,32] fp32
    const float* y = (const float*)d_in[1];  // labels: [16,1024,32] fp32

    char* wsb = (char*)d_ws;
    _Float16* C  = (_Float16*)wsb;                       // 32 MB
    float* Sm    = (float*)(wsb + (32u << 20));          // 8 MB  [2048][1024]
    float* Ss    = (float*)(wsb + (40u << 20));          // 8 MB
    float* u     = (float*)(wsb + (48u << 20));          // 16384 floats
    float* v     = u + 16384;                            // 16384 floats
    float* err   = v + 16384;                            // [16][128]
    int*   dflag = (int*)(err + 2048);                   // 128
    float* out   = (float*)d_out;

    // u, v, err, dflag contiguous — zero them (+ out) every call
    (void)hipMemsetAsync(u, 0, (size_t)(2 * 16384 + 2048 + 128) * 4, stream);
    (void)hipMemsetAsync(out, 0, sizeof(float), stream);

    build_dist<<<dim3(16 * 64), dim3(256), 0, stream>>>(x, y, C);   // CT not needed

    for (int it = 0; it < MAX_ITER; ++it) {
        u_pass_fused<<<dim3(2048), dim3(256), 0, stream>>>(C, v, u, Sm, Ss, err, dflag, it);
        v_finish<<<dim3(256), dim3(256), 0, stream>>>(Sm, Ss, v, err, dflag, it);
    }

    cost_kernel<<<dim3(512), dim3(256), 0, stream>>>(C, u, v, out);
}